// Round 13
// baseline (119.841 us; speedup 1.0000x reference)
//
#include <hip/hip_runtime.h>
#include <hip/hip_bf16.h>

#define LSEQ   1024
#define NHEAD  8
#define DH     64
#define DIM    512
#define NHTOT  16
#define DF     192   // concatenated feature dim: [plain, cos, sin]
#define LDB    68    // ushort LDS row stride for proj tiles
#define LDQ    200   // ushort LDS row stride for 192-wide feature tiles (400 B)
#define LDV    72    // ushort LDS row stride for 64-wide tiles (144 B)

typedef __attribute__((ext_vector_type(8))) short short8;
typedef __attribute__((ext_vector_type(4))) float floatx4;

__device__ __forceinline__ float softplusf_(float x) {
    if (x > 20.f) return x;
    return log1pf(expf(x));
}
__device__ __forceinline__ unsigned short bf16_rne(float x) {
    unsigned int u = __float_as_uint(x);
    u += 0x7FFFu + ((u >> 16) & 1u);
    return (unsigned short)(u >> 16);
}
__device__ __forceinline__ float bf16_tof(unsigned short h) {
    return __uint_as_float(((unsigned int)h) << 16);
}

// ---------------------------------------------------------------------------
// Kernel A: projections + feature map.  C = X @ W^T (bf16 MFMA, 64x64 tile).
// sel 0: q -> Q' = [softplus(q), q'*cos(l*w+bias), q'*sin(l*w+bias)]  (192-d)
// sel 1: k -> K' = [softplus(k), k'*cos(l*w),      k'*sin(l*w)]       (192-d)
// sel 2: v -> raw bf16 (64-d)
// ---------------------------------------------------------------------------
__global__ __launch_bounds__(256) void proj_kernel(
    const float* __restrict__ query, const float* __restrict__ key,
    const float* __restrict__ Wq, const float* __restrict__ Wk,
    const float* __restrict__ Wv,
    const float* __restrict__ pw, const float* __restrict__ pb,
    unsigned short* __restrict__ qf, unsigned short* __restrict__ kf,
    unsigned short* __restrict__ vbuf)
{
    const int mt  = blockIdx.x;
    const int ot  = blockIdx.y;
    const int sel = blockIdx.z;
    const int t   = threadIdx.x;

    const float* __restrict__ X = (sel == 0) ? query : key;
    const float* __restrict__ W = (sel == 0) ? Wq : (sel == 1) ? Wk : Wv;

    __shared__ unsigned short As[64 * LDB];
    __shared__ unsigned short Bs[64 * LDB];

    const int m0 = mt * 64, o0 = ot * 64;
    const int lane = t & 63, wave = t >> 6;
    const int quad = lane >> 4, l16 = lane & 15;
    const int wm = wave >> 1, wn = wave & 1;

    const int srow = t >> 2;
    const int sc16 = (t & 3) * 16;

    floatx4 acc[2][2];
    #pragma unroll
    for (int i = 0; i < 2; ++i)
        #pragma unroll
        for (int j = 0; j < 2; ++j) acc[i][j] = (floatx4){0.f, 0.f, 0.f, 0.f};

    float4 ax[4], bx4[4];
    #pragma unroll
    for (int i = 0; i < 4; ++i) {
        ax[i]  = *(const float4*)&X[(size_t)(m0 + srow) * DIM + sc16 + i * 4];
        bx4[i] = *(const float4*)&W[(size_t)(o0 + srow) * DIM + sc16 + i * 4];
    }

    for (int kt = 0; kt < DIM; kt += 64) {
        __syncthreads();
        {
            short8 a0, a1, b0, b1;
            #pragma unroll
            for (int i = 0; i < 2; ++i) {
                const float va[4] = {ax[i].x, ax[i].y, ax[i].z, ax[i].w};
                const float vb[4] = {bx4[i].x, bx4[i].y, bx4[i].z, bx4[i].w};
                #pragma unroll
                for (int j = 0; j < 4; ++j) {
                    a0[i * 4 + j] = (short)bf16_rne(va[j]);
                    b0[i * 4 + j] = (short)bf16_rne(vb[j]);
                }
            }
            #pragma unroll
            for (int i = 2; i < 4; ++i) {
                const float va[4] = {ax[i].x, ax[i].y, ax[i].z, ax[i].w};
                const float vb[4] = {bx4[i].x, bx4[i].y, bx4[i].z, bx4[i].w};
                #pragma unroll
                for (int j = 0; j < 4; ++j) {
                    a1[(i - 2) * 4 + j] = (short)bf16_rne(va[j]);
                    b1[(i - 2) * 4 + j] = (short)bf16_rne(vb[j]);
                }
            }
            *(short8*)&As[srow * LDB + sc16]     = a0;
            *(short8*)&As[srow * LDB + sc16 + 8] = a1;
            *(short8*)&Bs[srow * LDB + sc16]     = b0;
            *(short8*)&Bs[srow * LDB + sc16 + 8] = b1;
        }
        __syncthreads();

        if (kt + 64 < DIM) {
            #pragma unroll
            for (int i = 0; i < 4; ++i) {
                ax[i]  = *(const float4*)&X[(size_t)(m0 + srow) * DIM + kt + 64 + sc16 + i * 4];
                bx4[i] = *(const float4*)&W[(size_t)(o0 + srow) * DIM + kt + 64 + sc16 + i * 4];
            }
        }

        #pragma unroll
        for (int s = 0; s < 2; ++s) {
            short8 af[2], bf[2];
            #pragma unroll
            for (int mi = 0; mi < 2; ++mi)
                af[mi] = *(const short8*)&As[(wm * 32 + mi * 16 + l16) * LDB + s * 32 + quad * 8];
            #pragma unroll
            for (int ni = 0; ni < 2; ++ni)
                bf[ni] = *(const short8*)&Bs[(wn * 32 + ni * 16 + l16) * LDB + s * 32 + quad * 8];
            #pragma unroll
            for (int ni = 0; ni < 2; ++ni)
                #pragma unroll
                for (int mi = 0; mi < 2; ++mi)
                    acc[mi][ni] = __builtin_amdgcn_mfma_f32_16x16x32_bf16(af[mi], bf[ni], acc[mi][ni], 0, 0, 0);
        }
    }

    const int h = ot;   // o0 = h*64
    const float PI_ = 3.14159265358979323846f;
    if (sel == 2) {
        #pragma unroll
        for (int mi = 0; mi < 2; ++mi)
            #pragma unroll
            for (int ni = 0; ni < 2; ++ni) {
                const int d = wn * 32 + ni * 16 + l16;
                #pragma unroll
                for (int r = 0; r < 4; ++r) {
                    const int m = m0 + wm * 32 + mi * 16 + quad * 4 + r;
                    const int n = m >> 10, l = m & (LSEQ - 1);
                    vbuf[(((size_t)(n * NHEAD + h)) * LSEQ + l) * DH + d] =
                        bf16_rne(acc[mi][ni][r]);
                }
            }
    } else {
        unsigned short* __restrict__ obuf = (sel == 0) ? qf : kf;
        #pragma unroll
        for (int ni = 0; ni < 2; ++ni) {
            const int d = wn * 32 + ni * 16 + l16;
            const float w = pw[h * DH + d];
            const float bias = (sel == 0) ? PI_ / (1.f + expf(-pb[h * DH + d])) : 0.f;
            #pragma unroll
            for (int mi = 0; mi < 2; ++mi)
                #pragma unroll
                for (int r = 0; r < 4; ++r) {
                    const int m = m0 + wm * 32 + mi * 16 + quad * 4 + r;
                    const int n = m >> 10, l = m & (LSEQ - 1);
                    const float val = softplusf_(acc[mi][ni][r]);
                    float sn, cs;
                    sincosf((float)l * w + bias, &sn, &cs);
                    const size_t ob = (((size_t)(n * NHEAD + h)) * LSEQ + l) * DF + d;
                    obuf[ob]            = bf16_rne(val);
                    obuf[ob + DH]       = bf16_rne(val * cs);
                    obuf[ob + 2 * DH]   = bf16_rne(val * sn);
                }
        }
    }
}

// ---------------------------------------------------------------------------
// Kernel B (flash-style quadratic attention, register-prefetch pipelined):
//   S = tril(Q' K'^T);  out = (S V) / rowsum(S)
// Grid (p, nh, z) = (16,16,2) = 512 blocks (2/CU); z-pairing balances load.
// Next k-tile's K'/V global loads issue BEFORE this tile's GEMMs (the
// s_waitcnt lands after ~16 MFMAs instead of immediately), then commit to
// LDS after the post-GEMM2 barrier.  Same 3 syncs/iter as unpipelined.
// ---------------------------------------------------------------------------
__global__ __launch_bounds__(256) void attn_kernel(
    const unsigned short* __restrict__ qf, const unsigned short* __restrict__ kf,
    const unsigned short* __restrict__ vbuf,
    float* __restrict__ outp)
{
    const int p  = blockIdx.x;
    const int nh = blockIdx.y;
    const int z  = blockIdx.z;
    const int lt = z ? (31 - p) : p;       // 32-row l-tile index
    const int n  = nh >> 3;
    const int h  = nh & (NHEAD - 1);
    const int t  = threadIdx.x;
    const int lane = t & 63, wave = t >> 6;
    const int quad = lane >> 4, l16 = lane & 15;
    const int wm = wave >> 1, wn = wave & 1;   // wave tile: 16 rows x 32 cols

    __shared__ unsigned short qL[32 * LDQ];   // Q' tile [32][192]
    __shared__ unsigned short kL[64 * LDQ];   // K' tile [64][192]
    __shared__ unsigned short vT[64 * LDV];   // V^T tile [e][k]
    __shared__ unsigned short scA[32 * LDV];  // masked scores bf16 [l][k]
    __shared__ float denL[2][32];
    __shared__ float inv32[32];

    const size_t fbase = (size_t)nh * LSEQ;
    const int nkt = (lt >> 1) + 1;
    const int diag_kt = lt >> 1;

    // staging coordinates
    int krr[12], kcc[12];
    #pragma unroll
    for (int i = 0; i < 12; ++i) {
        const int idx = i * 256 + t;
        krr[i] = idx / 48;
        kcc[i] = (idx % 48) * 4;
    }
    const int vcol = t & 63, vkq = (t >> 6) * 16;

    // stage Q' + tile 0 of K'/V
    #pragma unroll
    for (int i = 0; i < 6; ++i) {
        const int idx = i * 256 + t;
        const int r = idx / 48, c4 = (idx % 48) * 4;
        *(ushort4*)&qL[r * LDQ + c4] =
            *(const ushort4*)&qf[(fbase + lt * 32 + r) * DF + c4];
    }
    #pragma unroll
    for (int i = 0; i < 12; ++i)
        *(ushort4*)&kL[krr[i] * LDQ + kcc[i]] =
            *(const ushort4*)&kf[(fbase + krr[i]) * DF + kcc[i]];
    {
        unsigned short vvv[16];
        #pragma unroll
        for (int j = 0; j < 16; ++j)
            vvv[j] = vbuf[(fbase + vkq + j) * DH + vcol];
        #pragma unroll
        for (int g = 0; g < 4; ++g) {
            ushort4 b;
            b.x = vvv[g * 4]; b.y = vvv[g * 4 + 1];
            b.z = vvv[g * 4 + 2]; b.w = vvv[g * 4 + 3];
            *(ushort4*)&vT[vcol * LDV + vkq + g * 4] = b;
        }
    }
    __syncthreads();

    floatx4 accN[2];
    accN[0] = (floatx4){0.f, 0.f, 0.f, 0.f};
    accN[1] = (floatx4){0.f, 0.f, 0.f, 0.f};
    float den4[4] = {0.f, 0.f, 0.f, 0.f};

    for (int kt = 0; kt < nkt; ++kt) {
        // ---- prefetch next tile into registers (loads issue now, waitcnt
        //      lands after the MFMAs below) ----
        ushort4 pk[12];
        unsigned short pv[16];
        const bool more = (kt + 1 < nkt);
        if (more) {
            const size_t nb = fbase + (size_t)(kt + 1) * 64;
            #pragma unroll
            for (int i = 0; i < 12; ++i)
                pk[i] = *(const ushort4*)&kf[(nb + krr[i]) * DF + kcc[i]];
            #pragma unroll
            for (int j = 0; j < 16; ++j)
                pv[j] = vbuf[(nb + vkq + j) * DH + vcol];
        }

        // GEMM1: scores(32x64) = Q'(32x192) . K'^T, K=192 in 6 steps
        floatx4 accS[2];
        accS[0] = (floatx4){0.f, 0.f, 0.f, 0.f};
        accS[1] = (floatx4){0.f, 0.f, 0.f, 0.f};
        #pragma unroll
        for (int kk = 0; kk < 6; ++kk) {
            const short8 a = *(const short8*)&qL[(wm * 16 + l16) * LDQ + kk * 32 + quad * 8];
            #pragma unroll
            for (int ni = 0; ni < 2; ++ni) {
                const short8 b = *(const short8*)&kL[(wn * 32 + ni * 16 + l16) * LDQ + kk * 32 + quad * 8];
                accS[ni] = __builtin_amdgcn_mfma_f32_16x16x32_bf16(a, b, accS[ni], 0, 0, 0);
            }
        }

        // mask (diagonal tile only), accumulate den (f32), write scA bf16
        const bool diag = (kt == diag_kt);
        #pragma unroll
        for (int ni = 0; ni < 2; ++ni) {
            const int kcolL = wn * 32 + ni * 16 + l16;
            const int kcolG = kt * 64 + kcolL;
            #pragma unroll
            for (int r = 0; r < 4; ++r) {
                const int lrowL = wm * 16 + quad * 4 + r;
                float sval = accS[ni][r];
                if (diag && kcolG > lt * 32 + lrowL) sval = 0.f;
                den4[r] += sval;
                scA[lrowL * LDV + kcolL] = bf16_rne(sval);
            }
        }
        __syncthreads();

        // GEMM2: num += scA(32x64) . V(64x64), K=64 in 2 steps
        #pragma unroll
        for (int kk = 0; kk < 2; ++kk) {
            const short8 a = *(const short8*)&scA[(wm * 16 + l16) * LDV + kk * 32 + quad * 8];
            #pragma unroll
            for (int ni = 0; ni < 2; ++ni) {
                const short8 b = *(const short8*)&vT[(wn * 32 + ni * 16 + l16) * LDV + kk * 32 + quad * 8];
                accN[ni] = __builtin_amdgcn_mfma_f32_16x16x32_bf16(a, b, accN[ni], 0, 0, 0);
            }
        }
        __syncthreads();   // all reads of kL/vT/scA done

        // ---- commit prefetched tile to LDS ----
        if (more) {
            #pragma unroll
            for (int i = 0; i < 12; ++i)
                *(ushort4*)&kL[krr[i] * LDQ + kcc[i]] = pk[i];
            #pragma unroll
            for (int g = 0; g < 4; ++g) {
                ushort4 b;
                b.x = pv[g * 4]; b.y = pv[g * 4 + 1];
                b.z = pv[g * 4 + 2]; b.w = pv[g * 4 + 3];
                *(ushort4*)&vT[vcol * LDV + vkq + g * 4] = b;
            }
            __syncthreads();
        }
    }

    // den: reduce den4 over the 16 l16-lanes of each quadrant, then across wn
    #pragma unroll
    for (int r = 0; r < 4; ++r) {
        float s = den4[r];
        s += __shfl_xor(s, 1);
        s += __shfl_xor(s, 2);
        s += __shfl_xor(s, 4);
        s += __shfl_xor(s, 8);
        if (l16 == 0) denL[wn][wm * 16 + quad * 4 + r] = s;
    }
    __syncthreads();
    if (t < 32) inv32[t] = 1.f / (denL[0][t] + denL[1][t]);
    __syncthreads();

    // out = num * (1/den)
    #pragma unroll
    for (int ni = 0; ni < 2; ++ni) {
        const int e = wn * 32 + ni * 16 + l16;
        #pragma unroll
        for (int r = 0; r < 4; ++r) {
            const int row = wm * 16 + quad * 4 + r;
            outp[((size_t)n * LSEQ + lt * 32 + row) * DIM + h * DH + e] =
                accN[ni][r] * inv32[row];
        }
    }
}

extern "C" void kernel_launch(void* const* d_in, const int* in_sizes, int n_in,
                              void* d_out, int out_size, void* d_ws, size_t ws_size,
                              hipStream_t stream) {
    const float* query = (const float*)d_in[0];
    const float* key   = (const float*)d_in[1];
    const float* Wq    = (const float*)d_in[2];
    const float* Wk    = (const float*)d_in[3];
    const float* Wv    = (const float*)d_in[4];
    const float* pw    = (const float*)d_in[5];
    const float* pb    = (const float*)d_in[6];

    unsigned short* U = (unsigned short*)d_ws;
    unsigned short* qf   = U;                 // 16*1024*192 = 3,145,728 u16
    unsigned short* kf   = U + 3145728;       // 3,145,728 u16
    unsigned short* vbuf = U + 6291456;       // 1,048,576 u16 -> 14.7 MB total

    proj_kernel<<<dim3(32, 8, 3), 256, 0, stream>>>(
        query, key, Wq, Wk, Wv, pw, pb, qf, kf, vbuf);
    attn_kernel<<<dim3(16, 16, 2), 256, 0, stream>>>(
        qf, kf, vbuf, (float*)d_out);
}